// Round 3
// baseline (234.043 us; speedup 1.0000x reference)
//
#include <hip/hip_runtime.h>

// SoftNormalShader: fused normal_shading + softmax_rgb_blend
// Layout R3: 2 lanes per pixel, 4 fragments per lane (k = 4h..4h+3).
// - dists/zbuf/p2f loaded as float4/int4: 16B/lane, perfectly coalesced
// - per-pixel reductions: in-register tree over 4 + single shfl_xor(1)
// - bary + face-normal gather only where softmax weight != 0 (exact:
//   exp((zi-zmax)/1e-4) underflows to 0.0f unless zi within ~0.0087 of max)
// N=4, H=512, W=512, K=8, V=50000, F=100000

constexpr int   N_PIX      = 4 * 512 * 512;
constexpr float INV_SIGMA  = 1.0f / 1e-4f;
constexpr float INV_GAMMA  = 1.0f / 1e-4f;
constexpr float ZFARV      = 100.0f;
constexpr float INV_ZRANGE = 1.0f / 99.0f;   // 1/(ZFAR-ZNEAR)
constexpr float EPSV       = 1e-10f;

// Prepass: pack gathered vertex normals per face into a 48B row
// (4.8MB table, L2/L3-resident) so the hot kernel does 3x dwordx4 gathers
// instead of 12x dword gathers per active fragment.
__global__ __launch_bounds__(256)
void build_face_normals_kernel(const float* __restrict__ vn,
                               const int*   __restrict__ faces,
                               float*       __restrict__ fn,
                               int nf)
{
    int f = blockIdx.x * blockDim.x + threadIdx.x;
    if (f >= nf) return;
    int v0 = faces[3 * f + 0];
    int v1 = faces[3 * f + 1];
    int v2 = faces[3 * f + 2];
    const float* p0 = vn + 3 * (size_t)v0;
    const float* p1 = vn + 3 * (size_t)v1;
    const float* p2 = vn + 3 * (size_t)v2;
    float4 r0 = make_float4(p0[0], p0[1], p0[2], p1[0]);
    float4 r1 = make_float4(p1[1], p1[2], p2[0], p2[1]);
    float4 r2 = make_float4(p2[2], 0.f, 0.f, 0.f);
    float4* dst = reinterpret_cast<float4*>(fn + 12 * (size_t)f);
    dst[0] = r0; dst[1] = r1; dst[2] = r2;
}

__global__ __launch_bounds__(256)
void shade_kernel(const float* __restrict__ bary,
                  const float* __restrict__ dists,
                  const float* __restrict__ zbuf,
                  const int*   __restrict__ p2f,
                  const float* __restrict__ fn,     // packed table (or null)
                  const float* __restrict__ vn,     // fallback path
                  const int*   __restrict__ faces,  // fallback path
                  float*       __restrict__ out)
{
    int gid = blockIdx.x * blockDim.x + threadIdx.x;  // 2 threads per pixel
    int h   = gid & 1;                                 // half: k = 4h..4h+3
    int pix = gid >> 1;
    if (pix >= N_PIX) return;

    // Coalesced 16B/lane streaming loads; fragment ids are 4*gid + k.
    float4 d4 = reinterpret_cast<const float4*>(dists)[gid];
    float4 z4 = reinterpret_cast<const float4*>(zbuf)[gid];
    int4   f4 = reinterpret_cast<const int4*>(p2f)[gid];

    float dk[4] = {d4.x, d4.y, d4.z, d4.w};
    float zk[4] = {z4.x, z4.y, z4.z, z4.w};
    int   fk[4] = {f4.x, f4.y, f4.z, f4.w};

    float pr[4], zi[4];
#pragma unroll
    for (int k = 0; k < 4; ++k) {
        bool m = fk[k] >= 0;
        // sigmoid(-d/sigma) = 1/(1+exp(d/sigma))
        pr[k] = m ? __builtin_amdgcn_rcpf(1.0f + __expf(dk[k] * INV_SIGMA)) : 0.0f;
        zi[k] = m ? (ZFARV - zk[k]) * INV_ZRANGE : 0.0f;
    }

    // Per-pixel max of z_inv: in-register tree + one cross-lane exchange.
    float zmax = fmaxf(fmaxf(zi[0], zi[1]), fmaxf(zi[2], zi[3]));
    zmax = fmaxf(zmax, __shfl_xor(zmax, 1));

    // alpha = prod(1 - prob)
    float am = (1.0f - pr[0]) * (1.0f - pr[1]) * (1.0f - pr[2]) * (1.0f - pr[3]);
    am *= __shfl_xor(am, 1);

    // Softmax weights + conditional gather/interp.
    float ws = 0.0f, cr = 0.0f, cg = 0.0f, cb = 0.0f;
#pragma unroll
    for (int k = 0; k < 4; ++k) {
        float w = pr[k] * __expf((zi[k] - zmax) * INV_GAMMA);
        ws += w;
        if (w != 0.0f) {               // implies fk[k] >= 0
            int f = fk[k];
            size_t bo = 12 * (size_t)gid + 3 * k;
            float b0 = bary[bo + 0];
            float b1 = bary[bo + 1];
            float b2 = bary[bo + 2];
            float n0x, n0y, n0z, n1x, n1y, n1z, n2x, n2y, n2z;
            if (fn) {
                const float4* frp = reinterpret_cast<const float4*>(fn + 12 * (size_t)f);
                float4 r0 = frp[0], r1 = frp[1], r2 = frp[2];
                n0x = r0.x; n0y = r0.y; n0z = r0.z;
                n1x = r0.w; n1y = r1.x; n1z = r1.y;
                n2x = r1.z; n2y = r1.w; n2z = r2.x;
            } else {
                int v0 = faces[3 * f + 0];
                int v1 = faces[3 * f + 1];
                int v2 = faces[3 * f + 2];
                n0x = vn[3 * v0 + 0]; n0y = vn[3 * v0 + 1]; n0z = vn[3 * v0 + 2];
                n1x = vn[3 * v1 + 0]; n1y = vn[3 * v1 + 1]; n1z = vn[3 * v1 + 2];
                n2x = vn[3 * v2 + 0]; n2y = vn[3 * v2 + 1]; n2z = vn[3 * v2 + 2];
            }
            cr += w * (b0 * n0x + b1 * n1x + b2 * n2x);
            cg += w * (b0 * n0y + b1 * n1y + b2 * n2y);
            cb += w * (b0 * n0z + b1 * n1z + b2 * n2z);
        }
    }

    // Cross-lane pair reduction (lane 2p <-> 2p+1).
    ws += __shfl_xor(ws, 1);
    cr += __shfl_xor(cr, 1);
    cg += __shfl_xor(cg, 1);
    cb += __shfl_xor(cb, 1);

    if (h == 0) {
        float delta     = fmaxf(__expf((EPSV - zmax) * INV_GAMMA), EPSV);
        float inv_denom = __builtin_amdgcn_rcpf(ws + delta);
        float4 o;
        o.x = (cr + delta) * inv_denom;   // background = (1,1,1)
        o.y = (cg + delta) * inv_denom;
        o.z = (cb + delta) * inv_denom;
        o.w = 1.0f - am;
        // Even lanes write 32 consecutive float4 -> dense 512B per wave.
        reinterpret_cast<float4*>(out)[pix] = o;
    }
}

extern "C" void kernel_launch(void* const* d_in, const int* in_sizes, int n_in,
                              void* d_out, int out_size, void* d_ws, size_t ws_size,
                              hipStream_t stream) {
    const float* vn    = (const float*)d_in[0];
    const float* bary  = (const float*)d_in[1];
    const float* dists = (const float*)d_in[2];
    const float* zbuf  = (const float*)d_in[3];
    const int*   faces = (const int*)d_in[4];
    const int*   p2f   = (const int*)d_in[5];
    float*       out   = (float*)d_out;

    int nf = in_sizes[4] / 3;

    float* fn = nullptr;
    size_t need = (size_t)nf * 12 * sizeof(float);
    if (ws_size >= need) {
        fn = (float*)d_ws;
        build_face_normals_kernel<<<(nf + 255) / 256, 256, 0, stream>>>(vn, faces, fn, nf);
    }

    int threads = N_PIX * 2;
    shade_kernel<<<threads / 256, 256, 0, stream>>>(bary, dists, zbuf, p2f,
                                                    fn, vn, faces, out);
}